// Round 1
// baseline (924.339 us; speedup 1.0000x reference)
//
#include <hip/hip_runtime.h>
#include <stdint.h>

// Problem constants (E, T, H, I) from the reference.
#define NE 64
#define NT 2048
#define NH 512
#define NI 1024

typedef __attribute__((ext_vector_type(8))) short bf16x8;
typedef __attribute__((ext_vector_type(4))) float f32x4;
typedef __attribute__((ext_vector_type(4))) uint32_t u32x4;

static __device__ __forceinline__ uint16_t f2bf(float f) {
  // RNE float->bf16 (inputs are well-behaved: no NaN/Inf in this problem)
  uint32_t u = __builtin_bit_cast(uint32_t, f);
  u += 0x7fffu + ((u >> 16) & 1u);
  return (uint16_t)(u >> 16);
}

static __device__ __forceinline__ float gelu_erf(float v) {
  // torch nn.GELU default = erf-based (reference uses approximate=False)
  return 0.5f * v * (1.0f + erff(v * 0.7071067811865475f));
}

// ---------------------------------------------------------------------------
// GEMM1 + GELU: h[e, t_local, i] = gelu( sum_k x[t,e,k] * wi[e,k,i] ), bf16 out
// Tile: BM=128 (t), BN=128 (i), BK=64. 256 threads = 4 waves (2x2), each wave
// owns a 64x64 sub-tile = 4x4 MFMA 16x16x32 tiles.
// LDS: As[128][64], Bs[128][64] bf16, XOR-swizzled in 16B (8-elem) groups:
//   elem (r, k) lives at r*64 + ((k>>3) ^ (r&7))*8 + (k&7)
// ---------------------------------------------------------------------------
__global__ __launch_bounds__(256, 2)
void k_gemm1_gelu(const float* __restrict__ x, const float* __restrict__ wi,
                  uint16_t* __restrict__ h, int t_start, int Ts) {
  const int Mt = Ts >> 7;               // tiles along T within this slice
  const int bid = blockIdx.x;
  const int bm = bid % Mt;              // fastest: T-tile (shares wi panel)
  const int bn = (bid / Mt) & 7;        // NI/128 = 8
  const int be = bid / (Mt * 8);
  const int t0 = bm << 7;
  const int n0 = bn << 7;

  __shared__ uint16_t As[128 * 64];
  __shared__ uint16_t Bs[128 * 64];

  const int tid = threadIdx.x;
  const int lane = tid & 63;
  const int wy = (tid >> 7) & 1;        // wave row (0..1)
  const int wx = (tid >> 6) & 1;        // wave col (0..1)

  // A staging: 1024 chunks of 8 floats (row-major, k-contig). 4 per thread.
  int arow[4], akg[4];
  const float* aP[4];
#pragma unroll
  for (int s = 0; s < 4; ++s) {
    const int c = (s << 8) + tid;
    arow[s] = c >> 3;
    akg[s] = c & 7;
    aP[s] = x + ((size_t)(t_start + t0 + arow[s]) * NE + be) * NH + (akg[s] << 3);
  }
  // B staging: lane k = tid&63, n-block = (tid>>6)*32 (+ s*8 per sub-chunk).
  const int bk = tid & 63;
  const float* bP = wi + ((size_t)be * NH + bk) * NI + n0 + ((tid >> 6) << 5);

  f32x4 acc[4][4];
#pragma unroll
  for (int i = 0; i < 4; ++i)
#pragma unroll
    for (int j = 0; j < 4; ++j) acc[i][j] = (f32x4){0.f, 0.f, 0.f, 0.f};

  f32x4 ar[4][2], br[4][2];
#pragma unroll
  for (int s = 0; s < 4; ++s) {
    ar[s][0] = *(const f32x4*)(aP[s]);
    ar[s][1] = *(const f32x4*)(aP[s] + 4);
    br[s][0] = *(const f32x4*)(bP + (s << 3));
    br[s][1] = *(const f32x4*)(bP + (s << 3) + 4);
  }

  const int KIT = NH >> 6;  // 8
  for (int it = 0; it < KIT; ++it) {
    __syncthreads();
    // regs -> LDS (with fp32->bf16 convert; B is transposed into [n][k])
#pragma unroll
    for (int s = 0; s < 4; ++s) {
      bf16x8 w;
#pragma unroll
      for (int u = 0; u < 4; ++u) {
        w[u] = (short)f2bf(ar[s][0][u]);
        w[u + 4] = (short)f2bf(ar[s][1][u]);
      }
      *(bf16x8*)&As[(arow[s] << 6) + ((akg[s] ^ (arow[s] & 7)) << 3)] = w;
      const int nb = ((tid >> 6) << 5) + (s << 3);
#pragma unroll
      for (int j = 0; j < 8; ++j) {
        const float v = (j < 4) ? br[s][0][j] : br[s][1][j & 3];
        const int nn = nb + j;
        Bs[(nn << 6) + (((bk >> 3) ^ (nn & 7)) << 3) + (bk & 7)] = f2bf(v);
      }
    }
    __syncthreads();
    // prefetch next K-tile into regs (hides HBM latency under the MFMAs)
    if (it + 1 < KIT) {
      const int k0 = (it + 1) << 6;
#pragma unroll
      for (int s = 0; s < 4; ++s) {
        ar[s][0] = *(const f32x4*)(aP[s] + k0);
        ar[s][1] = *(const f32x4*)(aP[s] + k0 + 4);
        const float* q = bP + (size_t)k0 * NI + (s << 3);
        br[s][0] = *(const f32x4*)q;
        br[s][1] = *(const f32x4*)(q + 4);
      }
    }
    // compute: 2 k-steps x 4x4 tiles
#pragma unroll
    for (int ks = 0; ks < 2; ++ks) {
      const int kg = (ks << 2) + (lane >> 4);
      bf16x8 af[4], bfr[4];
#pragma unroll
      for (int mi = 0; mi < 4; ++mi) {
        const int row = (wy << 6) + (mi << 4) + (lane & 15);
        af[mi] = *(const bf16x8*)&As[(row << 6) + ((kg ^ (row & 7)) << 3)];
      }
#pragma unroll
      for (int ni = 0; ni < 4; ++ni) {
        const int col = (wx << 6) + (ni << 4) + (lane & 15);
        bfr[ni] = *(const bf16x8*)&Bs[(col << 6) + ((kg ^ (col & 7)) << 3)];
      }
#pragma unroll
      for (int mi = 0; mi < 4; ++mi)
#pragma unroll
        for (int ni = 0; ni < 4; ++ni)
          acc[mi][ni] = __builtin_amdgcn_mfma_f32_16x16x32_bf16(
              af[mi], bfr[ni], acc[mi][ni], 0, 0, 0);
    }
  }

  // epilogue: gelu + bf16 store to workspace h[e][t_local][i]
#pragma unroll
  for (int mi = 0; mi < 4; ++mi) {
#pragma unroll
    for (int ni = 0; ni < 4; ++ni) {
      const int col = n0 + (wx << 6) + (ni << 4) + (lane & 15);
#pragma unroll
      for (int j = 0; j < 4; ++j) {
        const int r = t0 + (wy << 6) + (mi << 4) + ((lane >> 4) << 2) + j;
        h[((size_t)be * Ts + r) * NI + col] = f2bf(gelu_erf(acc[mi][ni][j]));
      }
    }
  }
}

// ---------------------------------------------------------------------------
// GEMM2: out[t, e, hc] = sum_i h[e, t_local, i] * wo[e, i, hc], fp32 out.
// Same structure; A (h) is already bf16 so staging is a straight 16B copy.
// ---------------------------------------------------------------------------
__global__ __launch_bounds__(256, 2)
void k_gemm2(const uint16_t* __restrict__ h, const float* __restrict__ wo,
             float* __restrict__ out, int t_start, int Ts) {
  const int Mt = Ts >> 7;
  const int bid = blockIdx.x;
  const int bm = bid % Mt;
  const int bn = (bid / Mt) & 3;        // NH/128 = 4
  const int be = bid / (Mt * 4);
  const int t0 = bm << 7;
  const int n0 = bn << 7;

  __shared__ uint16_t As[128 * 64];
  __shared__ uint16_t Bs[128 * 64];

  const int tid = threadIdx.x;
  const int lane = tid & 63;
  const int wy = (tid >> 7) & 1;
  const int wx = (tid >> 6) & 1;

  int arow[4], akg[4];
  const uint16_t* aP[4];
#pragma unroll
  for (int s = 0; s < 4; ++s) {
    const int c = (s << 8) + tid;
    arow[s] = c >> 3;
    akg[s] = c & 7;
    aP[s] = h + ((size_t)be * Ts + t0 + arow[s]) * NI + (akg[s] << 3);
  }
  const int bk = tid & 63;
  const float* bP = wo + ((size_t)be * NI + bk) * NH + n0 + ((tid >> 6) << 5);

  f32x4 acc[4][4];
#pragma unroll
  for (int i = 0; i < 4; ++i)
#pragma unroll
    for (int j = 0; j < 4; ++j) acc[i][j] = (f32x4){0.f, 0.f, 0.f, 0.f};

  u32x4 ar[4];
  f32x4 br[4][2];
#pragma unroll
  for (int s = 0; s < 4; ++s) {
    ar[s] = *(const u32x4*)(aP[s]);
    br[s][0] = *(const f32x4*)(bP + (s << 3));
    br[s][1] = *(const f32x4*)(bP + (s << 3) + 4);
  }

  const int KIT = NI >> 6;  // 16
  for (int it = 0; it < KIT; ++it) {
    __syncthreads();
#pragma unroll
    for (int s = 0; s < 4; ++s) {
      *(u32x4*)&As[(arow[s] << 6) + ((akg[s] ^ (arow[s] & 7)) << 3)] = ar[s];
      const int nb = ((tid >> 6) << 5) + (s << 3);
#pragma unroll
      for (int j = 0; j < 8; ++j) {
        const float v = (j < 4) ? br[s][0][j] : br[s][1][j & 3];
        const int nn = nb + j;
        Bs[(nn << 6) + (((bk >> 3) ^ (nn & 7)) << 3) + (bk & 7)] = f2bf(v);
      }
    }
    __syncthreads();
    if (it + 1 < KIT) {
      const int k0 = (it + 1) << 6;
#pragma unroll
      for (int s = 0; s < 4; ++s) {
        ar[s] = *(const u32x4*)(aP[s] + k0);
        const float* q = bP + (size_t)k0 * NH + (s << 3);
        br[s][0] = *(const f32x4*)q;
        br[s][1] = *(const f32x4*)(q + 4);
      }
    }
#pragma unroll
    for (int ks = 0; ks < 2; ++ks) {
      const int kg = (ks << 2) + (lane >> 4);
      bf16x8 af[4], bfr[4];
#pragma unroll
      for (int mi = 0; mi < 4; ++mi) {
        const int row = (wy << 6) + (mi << 4) + (lane & 15);
        af[mi] = *(const bf16x8*)&As[(row << 6) + ((kg ^ (row & 7)) << 3)];
      }
#pragma unroll
      for (int ni = 0; ni < 4; ++ni) {
        const int col = (wx << 6) + (ni << 4) + (lane & 15);
        bfr[ni] = *(const bf16x8*)&Bs[(col << 6) + ((kg ^ (col & 7)) << 3)];
      }
#pragma unroll
      for (int mi = 0; mi < 4; ++mi)
#pragma unroll
        for (int ni = 0; ni < 4; ++ni)
          acc[mi][ni] = __builtin_amdgcn_mfma_f32_16x16x32_bf16(
              af[mi], bfr[ni], acc[mi][ni], 0, 0, 0);
    }
  }

  // epilogue: fp32 store into out[t, e, hc] layout (16-lane = 64B runs)
#pragma unroll
  for (int mi = 0; mi < 4; ++mi) {
#pragma unroll
    for (int ni = 0; ni < 4; ++ni) {
      const int col = n0 + (wx << 6) + (ni << 4) + (lane & 15);
#pragma unroll
      for (int j = 0; j < 4; ++j) {
        const int r = t0 + (wy << 6) + (mi << 4) + ((lane >> 4) << 2) + j;
        out[((size_t)(t_start + r) * NE + be) * NH + col] = acc[mi][ni][j];
      }
    }
  }
}

extern "C" void kernel_launch(void* const* d_in, const int* in_sizes, int n_in,
                              void* d_out, int out_size, void* d_ws, size_t ws_size,
                              hipStream_t stream) {
  const float* x = (const float*)d_in[0];   // [T, E, H] fp32
  const float* wi = (const float*)d_in[1];  // [E, H, I] fp32
  const float* wo = (const float*)d_in[2];  // [E, I, H] fp32
  float* out = (float*)d_out;               // [T, E, H] fp32
  uint16_t* hws = (uint16_t*)d_ws;          // bf16 intermediate h

  // Full h needs E*T*I*2 = 256 MiB of workspace. If ws is smaller, process T
  // in slices of Ts rows (multiple of 128); kernels on the same stream
  // serialize, so gemm2 of a slice sees its completed h.
  const size_t needFull = (size_t)NE * NT * NI * 2;
  int Ts = NT;
  if (ws_size < needFull) {
    const size_t perSlice = (size_t)NE * 128 * NI * 2;  // 16 MiB
    int nSlices = (int)(ws_size / perSlice);
    Ts = nSlices * 128;
    if (Ts < 128) Ts = 128;  // below 16 MiB ws there is no valid plan; assume >=
    if (Ts > NT) Ts = NT;
  }

  for (int t_start = 0; t_start < NT; t_start += Ts) {
    int cur = NT - t_start;
    if (cur > Ts) cur = Ts;
    const int Mt = cur >> 7;
    hipLaunchKernelGGL(k_gemm1_gelu, dim3(Mt * 8 * NE), dim3(256), 0, stream,
                       x, wi, hws, t_start, cur);
    hipLaunchKernelGGL(k_gemm2, dim3(Mt * 4 * NE), dim3(256), 0, stream,
                       hws, wo, out, t_start, cur);
  }
}

// Round 2
// 755.881 us; speedup vs baseline: 1.2229x; 1.2229x over previous
//
#include <hip/hip_runtime.h>
#include <stdint.h>

#define NE 64
#define NT 2048
#define NH 512
#define NI 1024

typedef __attribute__((ext_vector_type(8))) short bf16x8;
typedef __attribute__((ext_vector_type(4))) float f32x4;

typedef const __attribute__((address_space(1))) void* gptr1_t;
typedef __attribute__((address_space(3))) void* lptr3_t;
#define GLOAD16(g, l) \
  __builtin_amdgcn_global_load_lds((gptr1_t)(const void*)(g), (lptr3_t)(void*)(l), 16, 0, 0)

static __device__ __forceinline__ uint16_t f2bf(float f) {
  uint32_t u = __builtin_bit_cast(uint32_t, f);
  u += 0x7fffu + ((u >> 16) & 1u);
  return (uint16_t)(u >> 16);
}

static __device__ __forceinline__ float gelu_erf(float v) {
  return 0.5f * v * (1.0f + erff(v * 0.7071067811865475f));
}

// ---------------------------------------------------------------------------
// transpose + cast: in[e][K][N] f32 -> out[e][N][K] bf16, 64x64 tiles per block
// ---------------------------------------------------------------------------
__global__ __launch_bounds__(256)
void conv_tr(const float* __restrict__ in, uint16_t* __restrict__ out, int K, int N) {
  const int e = blockIdx.x;
  const int k0 = blockIdx.y << 6;
  const int n0 = blockIdx.z << 6;
  __shared__ uint16_t t[64][72];  // +8 pad to spread banks
  const int tid = threadIdx.x;
  const int r = tid >> 2;          // 0..63
  const int c0 = (tid & 3) << 4;   // 0,16,32,48
  const float* ip = in + ((size_t)e * K + k0 + r) * N + n0 + c0;
#pragma unroll
  for (int j = 0; j < 16; j += 4) {
    f32x4 v = *(const f32x4*)(ip + j);
#pragma unroll
    for (int u = 0; u < 4; ++u) t[c0 + j + u][r] = f2bf(v[u]);
  }
  __syncthreads();
  uint16_t* op = out + ((size_t)e * N + n0 + r) * K + k0 + c0;
  *(bf16x8*)op = *(const bf16x8*)&t[r][c0];
  *(bf16x8*)(op + 8) = *(const bf16x8*)&t[r][c0 + 8];
}

// ---------------------------------------------------------------------------
// GEMM1 + GELU: h[e,t,i] = gelu( x[t,e,:] . wi'[e,i,:] ), bf16 out.
// 128x128x64 tile, 4 waves (2x2), 4x4 16x16x32 MFMA per wave.
// B: global_load_lds w/ swizzled SOURCE address (LDS dest linear).
// A: fp32 x -> reg -> f2bf -> swizzled ds_write_b128 (2-iter reg pipeline).
// LDS XOR swizzle: elem (r,k) at r*64 + ((k>>3)^(r&7))*8 + (k&7).
// ---------------------------------------------------------------------------
__global__ __launch_bounds__(256, 2)
void k_gemm1(const float* __restrict__ x, const uint16_t* __restrict__ wiB,
             uint16_t* __restrict__ h, int t_start, int Ts) {
  const int Mt = Ts >> 7;
  const int nwg = gridDim.x;  // Mt*8*64, divisible by 8
  const int wid = (blockIdx.x & 7) * (nwg >> 3) + (blockIdx.x >> 3);  // XCD chunk
  const int bn = wid & 7;            // fastest: n-tile (A panel L2-reuse)
  const int bm = (wid >> 3) % Mt;
  const int be = wid / (Mt << 3);
  const int t0 = bm << 7, n0 = bn << 7;

  __shared__ __align__(16) uint16_t As[2][8192];
  __shared__ __align__(16) uint16_t Bs[2][8192];

  const int tid = threadIdx.x, lane = tid & 63;
  const int wy = (tid >> 7) & 1, wx = (tid >> 6) & 1;

  const uint16_t* Bbase = wiB + ((size_t)be << 19) + ((size_t)n0 << 9);

  int bOff[4], ldsOff[4], aLds[4];
  const float* aP[4];
#pragma unroll
  for (int s = 0; s < 4; ++s) {
    const int c = (s << 8) + tid;
    const int rr = c >> 3, kgs = c & 7;
    bOff[s] = (rr << 9) + ((kgs ^ (rr & 7)) << 3);   // swizzled global src (elems)
    ldsOff[s] = c << 4;                              // linear LDS dest (bytes)
    aP[s] = x + ((size_t)(t_start + t0 + rr) * NE + be) * NH + (kgs << 3);
    aLds[s] = (rr << 6) + ((kgs ^ (rr & 7)) << 3);   // swizzled LDS dest (elems)
  }

  f32x4 ar[4][2];
  f32x4 acc[4][4];
#pragma unroll
  for (int i = 0; i < 4; ++i)
#pragma unroll
    for (int j = 0; j < 4; ++j) acc[i][j] = (f32x4){0.f, 0.f, 0.f, 0.f};

  auto loadA = [&](int it) {
#pragma unroll
    for (int s = 0; s < 4; ++s) {
      ar[s][0] = *(const f32x4*)(aP[s] + (it << 6));
      ar[s][1] = *(const f32x4*)(aP[s] + (it << 6) + 4);
    }
  };
  auto writeA = [&](int buf) {
#pragma unroll
    for (int s = 0; s < 4; ++s) {
      bf16x8 w;
#pragma unroll
      for (int u = 0; u < 4; ++u) {
        w[u] = (short)f2bf(ar[s][0][u]);
        w[u + 4] = (short)f2bf(ar[s][1][u]);
      }
      *(bf16x8*)&As[buf][aLds[s]] = w;
    }
  };
  auto stageB = [&](int it, int buf) {
#pragma unroll
    for (int s = 0; s < 4; ++s)
      GLOAD16(Bbase + (it << 6) + bOff[s], (char*)&Bs[buf][0] + ldsOff[s]);
  };
  auto compute = [&](int cur) {
#pragma unroll
    for (int ks = 0; ks < 2; ++ks) {
      const int kg = (ks << 2) + (lane >> 4);
      bf16x8 af[4], bfr[4];
#pragma unroll
      for (int mi = 0; mi < 4; ++mi) {
        const int row = (wy << 6) + (mi << 4) + (lane & 15);
        af[mi] = *(const bf16x8*)&As[cur][(row << 6) + ((kg ^ (row & 7)) << 3)];
      }
#pragma unroll
      for (int ni = 0; ni < 4; ++ni) {
        const int col = (wx << 6) + (ni << 4) + (lane & 15);
        bfr[ni] = *(const bf16x8*)&Bs[cur][(col << 6) + ((kg ^ (col & 7)) << 3)];
      }
#pragma unroll
      for (int mi = 0; mi < 4; ++mi)
#pragma unroll
        for (int ni = 0; ni < 4; ++ni)
          acc[mi][ni] = __builtin_amdgcn_mfma_f32_16x16x32_bf16(
              af[mi], bfr[ni], acc[mi][ni], 0, 0, 0);
    }
  };

  loadA(0);
  stageB(0, 0);
  writeA(0);
  loadA(1);
  const int KIT = NH >> 6;  // 8
  for (int it = 0; it < KIT; ++it) {
    __syncthreads();  // drains vmcnt+lgkm: buf[it&1] ready; all waves done w/ buf[(it+1)&1]
    if (it + 1 < KIT) {
      stageB(it + 1, (it + 1) & 1);
      writeA((it + 1) & 1);  // ar holds tile it+1
      if (it + 2 < KIT) loadA(it + 2);
    }
    compute(it & 1);
  }

#pragma unroll
  for (int mi = 0; mi < 4; ++mi) {
#pragma unroll
    for (int ni = 0; ni < 4; ++ni) {
      const int col = n0 + (wx << 6) + (ni << 4) + (lane & 15);
#pragma unroll
      for (int j = 0; j < 4; ++j) {
        const int r = t0 + (wy << 6) + (mi << 4) + ((lane >> 4) << 2) + j;
        h[((size_t)be * Ts + r) * NI + col] = f2bf(gelu_erf(acc[mi][ni][j]));
      }
    }
  }
}

// ---------------------------------------------------------------------------
// GEMM2: out[t,e,hc] = h[e,t,:] . wo'[e,hc,:], fp32 out. Both operands bf16 ->
// both staged via global_load_lds with swizzled source.
// ---------------------------------------------------------------------------
__global__ __launch_bounds__(256, 2)
void k_gemm2(const uint16_t* __restrict__ hA, const uint16_t* __restrict__ woB,
             float* __restrict__ out, int t_start, int Ts) {
  const int Mt = Ts >> 7;
  const int nwg = gridDim.x;  // Mt*4*64
  const int wid = (blockIdx.x & 7) * (nwg >> 3) + (blockIdx.x >> 3);
  const int bn = wid & 3;
  const int bm = (wid >> 2) % Mt;
  const int be = wid / (Mt << 2);
  const int t0 = bm << 7, n0 = bn << 7;

  __shared__ __align__(16) uint16_t As[2][8192];
  __shared__ __align__(16) uint16_t Bs[2][8192];

  const int tid = threadIdx.x, lane = tid & 63;
  const int wy = (tid >> 7) & 1, wx = (tid >> 6) & 1;

  const uint16_t* Abase = hA + ((size_t)be * Ts + t0) * NI;
  const uint16_t* Bbase = woB + ((size_t)be << 19) + ((size_t)n0 << 10);

  int off[4], ldsOff[4];
#pragma unroll
  for (int s = 0; s < 4; ++s) {
    const int c = (s << 8) + tid;
    const int rr = c >> 3, kgs = c & 7;
    off[s] = (rr << 10) + ((kgs ^ (rr & 7)) << 3);  // row stride NI for both A,B
    ldsOff[s] = c << 4;
  }

  f32x4 acc[4][4];
#pragma unroll
  for (int i = 0; i < 4; ++i)
#pragma unroll
    for (int j = 0; j < 4; ++j) acc[i][j] = (f32x4){0.f, 0.f, 0.f, 0.f};

  auto stage = [&](int it, int buf) {
#pragma unroll
    for (int s = 0; s < 4; ++s)
      GLOAD16(Abase + (it << 6) + off[s], (char*)&As[buf][0] + ldsOff[s]);
#pragma unroll
    for (int s = 0; s < 4; ++s)
      GLOAD16(Bbase + (it << 6) + off[s], (char*)&Bs[buf][0] + ldsOff[s]);
  };
  auto compute = [&](int cur) {
#pragma unroll
    for (int ks = 0; ks < 2; ++ks) {
      const int kg = (ks << 2) + (lane >> 4);
      bf16x8 af[4], bfr[4];
#pragma unroll
      for (int mi = 0; mi < 4; ++mi) {
        const int row = (wy << 6) + (mi << 4) + (lane & 15);
        af[mi] = *(const bf16x8*)&As[cur][(row << 6) + ((kg ^ (row & 7)) << 3)];
      }
#pragma unroll
      for (int ni = 0; ni < 4; ++ni) {
        const int col = (wx << 6) + (ni << 4) + (lane & 15);
        bfr[ni] = *(const bf16x8*)&Bs[cur][(col << 6) + ((kg ^ (col & 7)) << 3)];
      }
#pragma unroll
      for (int mi = 0; mi < 4; ++mi)
#pragma unroll
        for (int ni = 0; ni < 4; ++ni)
          acc[mi][ni] = __builtin_amdgcn_mfma_f32_16x16x32_bf16(
              af[mi], bfr[ni], acc[mi][ni], 0, 0, 0);
    }
  };

  stage(0, 0);
  const int KIT = NI >> 6;  // 16
  for (int it = 0; it < KIT; ++it) {
    __syncthreads();
    if (it + 1 < KIT) stage(it + 1, (it + 1) & 1);
    compute(it & 1);
  }

#pragma unroll
  for (int mi = 0; mi < 4; ++mi) {
#pragma unroll
    for (int ni = 0; ni < 4; ++ni) {
      const int col = n0 + (wx << 6) + (ni << 4) + (lane & 15);
#pragma unroll
      for (int j = 0; j < 4; ++j) {
        const int r = t0 + (wy << 6) + (mi << 4) + ((lane >> 4) << 2) + j;
        out[((size_t)(t_start + r) * NE + be) * NH + col] = acc[mi][ni][j];
      }
    }
  }
}

extern "C" void kernel_launch(void* const* d_in, const int* in_sizes, int n_in,
                              void* d_out, int out_size, void* d_ws, size_t ws_size,
                              hipStream_t stream) {
  const float* x = (const float*)d_in[0];   // [T, E, H] fp32
  const float* wi = (const float*)d_in[1];  // [E, H, I] fp32
  const float* wo = (const float*)d_in[2];  // [E, I, H] fp32
  float* out = (float*)d_out;

  // ws layout: wi' bf16 [E][I][H] (64 MiB) | wo' bf16 [E][H][I] (64 MiB) | h slices
  uint16_t* wiB = (uint16_t*)d_ws;
  uint16_t* woB = (uint16_t*)((char*)d_ws + 67108864);
  uint16_t* h = (uint16_t*)((char*)d_ws + 134217728);

  const size_t havail = ws_size - 134217728;
  int Ts = (int)(havail / ((size_t)NE * NI * 2));  // 131072 B per t-row
  Ts &= ~127;
  if (Ts > NT) Ts = NT;
  if (Ts < 128) Ts = 128;  // round 1 proved ws >= 256 MiB, so Ts >= 1024

  hipLaunchKernelGGL(conv_tr, dim3(NE, NH / 64, NI / 64), dim3(256), 0, stream,
                     wi, wiB, NH, NI);
  hipLaunchKernelGGL(conv_tr, dim3(NE, NI / 64, NH / 64), dim3(256), 0, stream,
                     wo, woB, NI, NH);

  for (int ts = 0; ts < NT; ts += Ts) {
    int cur = NT - ts;
    if (cur > Ts) cur = Ts;
    const int Mt = cur >> 7;
    hipLaunchKernelGGL(k_gemm1, dim3(Mt * 8 * NE), dim3(256), 0, stream,
                       x, wiB, h, ts, cur);
    hipLaunchKernelGGL(k_gemm2, dim3(Mt * 4 * NE), dim3(256), 0, stream,
                       h, woB, out, ts, cur);
  }
}

// Round 3
// 563.936 us; speedup vs baseline: 1.6391x; 1.3404x over previous
//
#include <hip/hip_runtime.h>
#include <stdint.h>

#define NE 64
#define NT 2048
#define NH 512
#define NI 1024

typedef __attribute__((ext_vector_type(8))) short bf16x8;
typedef __attribute__((ext_vector_type(4))) float f32x4;

typedef const __attribute__((address_space(1))) void* gptr1_t;
typedef __attribute__((address_space(3))) void* lptr3_t;
#define GLOAD16(g, l) \
  __builtin_amdgcn_global_load_lds((gptr1_t)(const void*)(g), (lptr3_t)(void*)(l), 16, 0, 0)

static __device__ __forceinline__ uint16_t f2bf(float f) {
  uint32_t u = __builtin_bit_cast(uint32_t, f);
  u += 0x7fffu + ((u >> 16) & 1u);
  return (uint16_t)(u >> 16);
}

static __device__ __forceinline__ float gelu_erf(float v) {
  return 0.5f * v * (1.0f + erff(v * 0.7071067811865475f));
}

// ---------------------------------------------------------------------------
// cast_x: x[t_start+t][e][:] f32 -> xB[e][t][:] bf16 (per-expert row-major A)
// ---------------------------------------------------------------------------
__global__ __launch_bounds__(256)
void cast_x(const float* __restrict__ x, uint16_t* __restrict__ xB,
            int t_start, int S) {
  const int total = S * NE * (NH / 8);
  for (int c = blockIdx.x * 256 + threadIdx.x; c < total; c += gridDim.x * 256) {
    const int hb = c & 63;
    const int e = (c >> 6) & 63;
    const int t = c >> 12;
    const float* ip = x + ((size_t)(t_start + t) * NE + e) * NH + (hb << 3);
    const f32x4 v0 = *(const f32x4*)ip;
    const f32x4 v1 = *(const f32x4*)(ip + 4);
    bf16x8 w;
#pragma unroll
    for (int u = 0; u < 4; ++u) {
      w[u] = (short)f2bf(v0[u]);
      w[u + 4] = (short)f2bf(v1[u]);
    }
    *(bf16x8*)&xB[((size_t)e * S + t) * NH + (hb << 3)] = w;
  }
}

// ---------------------------------------------------------------------------
// transpose + cast: in[e][K][N] f32 -> out[e][N][K] bf16, 64x64 tiles
// ---------------------------------------------------------------------------
__global__ __launch_bounds__(256)
void conv_tr(const float* __restrict__ in, uint16_t* __restrict__ out, int K, int N) {
  const int e = blockIdx.x;
  const int k0 = blockIdx.y << 6;
  const int n0 = blockIdx.z << 6;
  __shared__ uint16_t t[64][72];
  const int tid = threadIdx.x;
  const int r = tid >> 2;
  const int c0 = (tid & 3) << 4;
  const float* ip = in + ((size_t)e * K + k0 + r) * N + n0 + c0;
#pragma unroll
  for (int j = 0; j < 16; j += 4) {
    f32x4 v = *(const f32x4*)(ip + j);
#pragma unroll
    for (int u = 0; u < 4; ++u) t[c0 + j + u][r] = f2bf(v[u]);
  }
  __syncthreads();
  uint16_t* op = out + ((size_t)e * N + n0 + r) * K + k0 + c0;
  *(bf16x8*)op = *(const bf16x8*)&t[r][c0];
  *(bf16x8*)(op + 8) = *(const bf16x8*)&t[r][c0 + 8];
}

// ---------------------------------------------------------------------------
// GEMM1 + GELU: h[e,t,i] = gelu( xB[e,t,:] . wi'[e,i,:] ), bf16 out.
// m97 structure: 128x128x64 tile, single 32 KiB LDS buffer, 2 barriers/K-step,
// both operands staged via global_load_lds with XOR-swizzled SOURCE address
// (LDS dest linear). 4 waves (2x2), 4x4 16x16x32 MFMA per wave.
// LDS layout: elem (r,k) at r*64 + ((k>>3)^(r&7))*8 + (k&7).
// ---------------------------------------------------------------------------
__global__ __launch_bounds__(256, 3)
void k_gemm1(const uint16_t* __restrict__ xB, const uint16_t* __restrict__ wiB,
             uint16_t* __restrict__ h, int Ts) {
  const int Mt = Ts >> 7;
  const int nwg = gridDim.x;  // Mt*8*64, divisible by 8
  const int wid = (blockIdx.x & 7) * (nwg >> 3) + (blockIdx.x >> 3);
  const int bn = wid & 7;
  const int bm = (wid >> 3) % Mt;
  const int be = wid / (Mt << 3);
  const int t0 = bm << 7, n0 = bn << 7;

  __shared__ __align__(16) uint16_t As[8192];
  __shared__ __align__(16) uint16_t Bs[8192];

  const int tid = threadIdx.x, lane = tid & 63;
  const int wy = (tid >> 7) & 1, wx = (tid >> 6) & 1;

  const uint16_t* Abase = xB + ((size_t)be * Ts + t0) * NH;
  const uint16_t* Bbase = wiB + ((size_t)be * NI + n0) * NH;

  int off[4], ldsOff[4];
#pragma unroll
  for (int s = 0; s < 4; ++s) {
    const int c = (s << 8) + tid;
    const int rr = c >> 3, kgs = c & 7;
    off[s] = (rr << 9) + ((kgs ^ (rr & 7)) << 3);  // row stride NH=512
    ldsOff[s] = c << 4;
  }

  f32x4 acc[4][4];
#pragma unroll
  for (int i = 0; i < 4; ++i)
#pragma unroll
    for (int j = 0; j < 4; ++j) acc[i][j] = (f32x4){0.f, 0.f, 0.f, 0.f};

  const int KIT = NH >> 6;  // 8
  for (int it = 0; it < KIT; ++it) {
    __syncthreads();  // all waves done reading the buffer
#pragma unroll
    for (int s = 0; s < 4; ++s)
      GLOAD16(Abase + (it << 6) + off[s], (char*)As + ldsOff[s]);
#pragma unroll
    for (int s = 0; s < 4; ++s)
      GLOAD16(Bbase + (it << 6) + off[s], (char*)Bs + ldsOff[s]);
    __syncthreads();  // vmcnt(0) drained before barrier -> buffer ready
#pragma unroll
    for (int ks = 0; ks < 2; ++ks) {
      const int kg = (ks << 2) + (lane >> 4);
      bf16x8 af[4], bfr[4];
#pragma unroll
      for (int mi = 0; mi < 4; ++mi) {
        const int row = (wy << 6) + (mi << 4) + (lane & 15);
        af[mi] = *(const bf16x8*)&As[(row << 6) + ((kg ^ (row & 7)) << 3)];
      }
#pragma unroll
      for (int ni = 0; ni < 4; ++ni) {
        const int col = (wx << 6) + (ni << 4) + (lane & 15);
        bfr[ni] = *(const bf16x8*)&Bs[(col << 6) + ((kg ^ (col & 7)) << 3)];
      }
#pragma unroll
      for (int mi = 0; mi < 4; ++mi)
#pragma unroll
        for (int ni = 0; ni < 4; ++ni)
          acc[mi][ni] = __builtin_amdgcn_mfma_f32_16x16x32_bf16(
              af[mi], bfr[ni], acc[mi][ni], 0, 0, 0);
    }
  }

#pragma unroll
  for (int mi = 0; mi < 4; ++mi) {
#pragma unroll
    for (int ni = 0; ni < 4; ++ni) {
      const int col = n0 + (wx << 6) + (ni << 4) + (lane & 15);
#pragma unroll
      for (int j = 0; j < 4; ++j) {
        const int r = t0 + (wy << 6) + (mi << 4) + ((lane >> 4) << 2) + j;
        h[((size_t)be * Ts + r) * NI + col] = f2bf(gelu_erf(acc[mi][ni][j]));
      }
    }
  }
}

// ---------------------------------------------------------------------------
// GEMM2: out[t,e,hc] = h[e,t,:] . wo'[e,hc,:], fp32 out. Same m97 structure.
// ---------------------------------------------------------------------------
__global__ __launch_bounds__(256, 3)
void k_gemm2(const uint16_t* __restrict__ hA, const uint16_t* __restrict__ woB,
             float* __restrict__ out, int t_start, int Ts) {
  const int Mt = Ts >> 7;
  const int nwg = gridDim.x;  // Mt*4*64
  const int wid = (blockIdx.x & 7) * (nwg >> 3) + (blockIdx.x >> 3);
  const int bn = wid & 3;
  const int bm = (wid >> 2) % Mt;
  const int be = wid / (Mt << 2);
  const int t0 = bm << 7, n0 = bn << 7;

  __shared__ __align__(16) uint16_t As[8192];
  __shared__ __align__(16) uint16_t Bs[8192];

  const int tid = threadIdx.x, lane = tid & 63;
  const int wy = (tid >> 7) & 1, wx = (tid >> 6) & 1;

  const uint16_t* Abase = hA + ((size_t)be * Ts + t0) * NI;
  const uint16_t* Bbase = woB + ((size_t)be * NH + n0) * NI;

  int off[4], ldsOff[4];
#pragma unroll
  for (int s = 0; s < 4; ++s) {
    const int c = (s << 8) + tid;
    const int rr = c >> 3, kgs = c & 7;
    off[s] = (rr << 10) + ((kgs ^ (rr & 7)) << 3);  // row stride NI=1024
    ldsOff[s] = c << 4;
  }

  f32x4 acc[4][4];
#pragma unroll
  for (int i = 0; i < 4; ++i)
#pragma unroll
    for (int j = 0; j < 4; ++j) acc[i][j] = (f32x4){0.f, 0.f, 0.f, 0.f};

  const int KIT = NI >> 6;  // 16
  for (int it = 0; it < KIT; ++it) {
    __syncthreads();
#pragma unroll
    for (int s = 0; s < 4; ++s)
      GLOAD16(Abase + (it << 6) + off[s], (char*)As + ldsOff[s]);
#pragma unroll
    for (int s = 0; s < 4; ++s)
      GLOAD16(Bbase + (it << 6) + off[s], (char*)Bs + ldsOff[s]);
    __syncthreads();
#pragma unroll
    for (int ks = 0; ks < 2; ++ks) {
      const int kg = (ks << 2) + (lane >> 4);
      bf16x8 af[4], bfr[4];
#pragma unroll
      for (int mi = 0; mi < 4; ++mi) {
        const int row = (wy << 6) + (mi << 4) + (lane & 15);
        af[mi] = *(const bf16x8*)&As[(row << 6) + ((kg ^ (row & 7)) << 3)];
      }
#pragma unroll
      for (int ni = 0; ni < 4; ++ni) {
        const int col = (wx << 6) + (ni << 4) + (lane & 15);
        bfr[ni] = *(const bf16x8*)&Bs[(col << 6) + ((kg ^ (col & 7)) << 3)];
      }
#pragma unroll
      for (int mi = 0; mi < 4; ++mi)
#pragma unroll
        for (int ni = 0; ni < 4; ++ni)
          acc[mi][ni] = __builtin_amdgcn_mfma_f32_16x16x32_bf16(
              af[mi], bfr[ni], acc[mi][ni], 0, 0, 0);
    }
  }

#pragma unroll
  for (int mi = 0; mi < 4; ++mi) {
#pragma unroll
    for (int ni = 0; ni < 4; ++ni) {
      const int col = n0 + (wx << 6) + (ni << 4) + (lane & 15);
#pragma unroll
      for (int j = 0; j < 4; ++j) {
        const int r = t0 + (wy << 6) + (mi << 4) + ((lane >> 4) << 2) + j;
        out[((size_t)(t_start + r) * NE + be) * NH + col] = acc[mi][ni][j];
      }
    }
  }
}

extern "C" void kernel_launch(void* const* d_in, const int* in_sizes, int n_in,
                              void* d_out, int out_size, void* d_ws, size_t ws_size,
                              hipStream_t stream) {
  const float* x = (const float*)d_in[0];   // [T, E, H] fp32
  const float* wi = (const float*)d_in[1];  // [E, H, I] fp32
  const float* wo = (const float*)d_in[2];  // [E, I, H] fp32
  float* out = (float*)d_out;

  // ws: wiB bf16 [E][I][H] (64MiB) | woB bf16 [E][H][I] (64MiB) | xB | h
  uint16_t* wiB = (uint16_t*)d_ws;
  uint16_t* woB = (uint16_t*)((char*)d_ws + 67108864);
  char* rest = (char*)d_ws + 134217728;

  // Per T-row: xB = E*H*2 = 64 KiB, h = E*I*2 = 128 KiB -> 192 KiB/row.
  const size_t perRow = (size_t)NE * NH * 2 + (size_t)NE * NI * 2;
  size_t avail = (ws_size > 134217728u) ? ws_size - 134217728u : 0;
  int Ts = (int)(avail / perRow);
  Ts &= ~127;
  if (Ts > NT) Ts = NT;
  if (Ts < 128) Ts = 128;  // ws known >= ~380 MiB from rounds 1-2

  uint16_t* xB = (uint16_t*)rest;
  uint16_t* h = (uint16_t*)(rest + (size_t)NE * Ts * NH * 2);

  hipLaunchKernelGGL(conv_tr, dim3(NE, NH / 64, NI / 64), dim3(256), 0, stream,
                     wi, wiB, NH, NI);
  hipLaunchKernelGGL(conv_tr, dim3(NE, NI / 64, NH / 64), dim3(256), 0, stream,
                     wo, woB, NI, NH);

  for (int ts = 0; ts < NT; ts += Ts) {
    int cur = NT - ts;
    if (cur > Ts) cur = Ts;
    const int Mt = cur >> 7;
    const int castGrid = (cur * NE * (NH / 8) + 255) / 256;
    hipLaunchKernelGGL(cast_x, dim3(castGrid < 2048 ? castGrid : 2048), dim3(256),
                       0, stream, x, xB, ts, cur);
    hipLaunchKernelGGL(k_gemm1, dim3(Mt * 8 * NE), dim3(256), 0, stream,
                       xB, wiB, h, cur);
    hipLaunchKernelGGL(k_gemm2, dim3(Mt * 4 * NE), dim3(256), 0, stream,
                       h, woB, out, ts, cur);
  }
}